// Round 11
// baseline (432.578 us; speedup 1.0000x reference)
//
#include <hip/hip_runtime.h>
#include <hip/hip_bf16.h>
#include <math.h>

#define K 4
#define F 513
#define B 4000
#define NIT 5
#define FB (F*B)
#define KB (K*B)      // 16000
#define FCH 8         // f-chunk for demix/final (R9-verified optimum; 4 regressed)
#define NFC 65        // ceil(513/8)
#define NBC 4         // b-chunks for v_kernel
#define BCH (B/NBC)   // 1000

// ---------------- persistent scratch: static device globals ------------------
// NOTE: __device__ globals are zero-initialized at module load; update_kernel
// re-zeroes both r2 buffers every call, so every launch begins clean (replay-safe).
__device__ float2 g_Wh[F*16];        // (F,4,4) complex fp32
__device__ float2 g_Vp[NBC*64*F];    // per-b-chunk partial V: (y, k*16+q, f)
__device__ float2 g_scale[F*4];      // (F,4) complex fp32
__device__ float  g_r2[2][KB];       // double-buffered r2 (atomicAdd from demix)

// ---------------- complex double helpers (tiny per-f solves only) -----------
struct cd { double re, im; };
__device__ inline cd mkcd(double r, double i){ cd z; z.re=r; z.im=i; return z; }
__device__ inline cd cmul(cd a, cd b){ return mkcd(a.re*b.re - a.im*b.im, a.re*b.im + a.im*b.re); }
__device__ inline cd cadd(cd a, cd b){ return mkcd(a.re+b.re, a.im+b.im); }
__device__ inline cd csub(cd a, cd b){ return mkcd(a.re-b.re, a.im-b.im); }
__device__ inline cd conj_(cd a){ return mkcd(a.re, -a.im); }
__device__ inline cd cdiv(cd a, cd b){
  double d = b.re*b.re + b.im*b.im;
  return mkcd((a.re*b.re + a.im*b.im)/d, (a.im*b.re - a.re*b.im)/d);
}

// x = inv(M)[:,kk] via cofactors (branch-free, no pivoting), full fp64.
__device__ inline void invcol4(const cd M[4][4], int kk, cd x[4]){
  int r0 = (kk==0)?1:0;
  int r1 = (kk<=1)?2:1;
  int r2 = (kk<=2)?3:2;
  cd cof[4];
  #pragma unroll
  for (int i=0;i<4;++i){
    int c0 = (i==0)?1:0;
    int c1 = (i<=1)?2:1;
    int c2 = (i<=2)?3:2;
    cd m = cadd(csub(cmul(M[r0][c0], csub(cmul(M[r1][c1],M[r2][c2]), cmul(M[r1][c2],M[r2][c1]))),
                     cmul(M[r0][c1], csub(cmul(M[r1][c0],M[r2][c2]), cmul(M[r1][c2],M[r2][c0])))),
                cmul(M[r0][c2], csub(cmul(M[r1][c0],M[r2][c1]), cmul(M[r1][c1],M[r2][c0]))));
    if ((kk+i)&1) m = mkcd(-m.re,-m.im);
    cof[i] = m;
  }
  cd det = mkcd(0.0,0.0);
  #pragma unroll
  for (int i=0;i<4;++i) det = cadd(det, cmul(M[kk][i], cof[i]));
  cd idet = cdiv(mkcd(1.0,0.0), det);
  #pragma unroll
  for (int i=0;i<4;++i) x[i] = cmul(cof[i], idet);
}

// ---------------- kernels ---------------------------------------------------

// partial r2 accumulated straight into g_r2[pb] via atomicAdd (65 adders per
// address over the dispatch, 16000 distinct dwords -> negligible contention).
// it0: Wh = I -> Y = X (identity iteration; g_Wh not yet written).
__global__ __launch_bounds__(256) void demix_part_kernel(
    const float* __restrict__ Xr, const float* __restrict__ Xi, int pb, int it0){
  int b = blockIdx.x*blockDim.x + threadIdx.x;
  if (b >= B) return;
  int y = blockIdx.y;
  int f0 = y*FCH, f1 = min(f0+FCH, F);
  float acc[K];
  #pragma unroll
  for (int s=0;s<K;++s) acc[s]=0.0f;
  for (int f=f0; f<f1; ++f){
    float xr[K], xi[K];
    #pragma unroll
    for (int c=0;c<K;++c){ int idx=c*FB + f*B + b; xr[c]=Xr[idx]; xi[c]=Xi[idx]; }
    if (it0){
      #pragma unroll
      for (int s=0;s<K;++s) acc[s] += xr[s]*xr[s] + xi[s]*xi[s];
    } else {
      const float2* w = g_Wh + f*16;
      #pragma unroll
      for (int s=0;s<K;++s){
        float yr=0.0f, yi=0.0f;
        #pragma unroll
        for (int c=0;c<K;++c){
          float2 ww = w[s*4+c];
          yr += ww.x*xr[c] - ww.y*xi[c];
          yi += ww.x*xi[c] + ww.y*xr[c];
        }
        acc[s] += yr*yr + yi*yi;
      }
    }
  }
  #pragma unroll
  for (int s=0;s<K;++s) atomicAdd(&g_r2[pb][s*B + b], acc[s]);
}

// Partial V over a b-chunk: Vp[y,k,ij,f] = (1/B) sum_{b in chunk y} phi[k,b] p[ij](f,b)
// phi computed inline from g_r2[pb].
__global__ __launch_bounds__(256, 4) void v_kernel(
    const float* __restrict__ Xr, const float* __restrict__ Xi, int pb){
  int f = blockIdx.x;
  int y = blockIdx.y;
  int tid = threadIdx.x;
  float acc[64];
  #pragma unroll
  for (int q=0;q<64;++q) acc[q]=0.0f;

  int b0 = y*BCH;
  for (int b = b0 + tid; b < b0 + BCH; b += 256){
    float phi[K];
    #pragma unroll
    for (int k=0;k<K;++k) phi[k] = 0.5f / sqrtf(g_r2[pb][k*B+b]);
    float xr[K], xi[K];
    #pragma unroll
    for (int c=0;c<K;++c){ int idx=c*FB + f*B + b; xr[c]=Xr[idx]; xi[c]=Xi[idx]; }
    float p[16];
    #pragma unroll
    for (int i=0;i<4;++i) p[i] = xr[i]*xr[i] + xi[i]*xi[i];
    int s = 4;
    #pragma unroll
    for (int i=0;i<4;++i){
      #pragma unroll
      for (int j=i+1;j<4;++j){
        p[s++] = xr[i]*xr[j] + xi[i]*xi[j];
        p[s++] = xi[i]*xr[j] - xr[i]*xi[j];
      }
    }
    #pragma unroll
    for (int k=0;k<K;++k){
      #pragma unroll
      for (int q=0;q<16;++q) acc[k*16+q] += phi[k]*p[q];
    }
  }

  int lane = tid & 63, wave = tid >> 6;
  // Multi-value butterfly: 63 shfl_xor; after 6 steps lane l holds (in acc[0])
  // the wave-wide sum of original acc[l].
  #pragma unroll
  for (int d=0; d<6; ++d){
    const int sh = 1<<d;
    const bool hi = (lane & sh) != 0;
    #pragma unroll
    for (int m=0; m<(32>>d); ++m){
      float keep = hi ? acc[2*m+1] : acc[2*m];   // static indices: no scratch
      float send = hi ? acc[2*m]   : acc[2*m+1];
      acc[m] = keep + __shfl_xor(send, sh);
    }
  }

  __shared__ float part[4*64];
  __shared__ float red[64];
  part[wave*64 + lane] = acc[0];
  __syncthreads();
  if (tid < 64){
    red[tid] = (part[tid] + part[64+tid] + part[128+tid] + part[192+tid]) * (1.0f/B);
  }
  __syncthreads();
  if (tid < 64){
    int k = tid >> 4, ij = tid & 15, i = ij >> 2, j = ij & 3;
    float re, im;
    if (i == j){ re = red[k*16 + i]; im = 0.0f; }
    else {
      int a = min(i,j), c2 = max(i,j);
      int pidx = (a==0) ? (c2-1) : ((a==1) ? (c2+1) : 5);
      re = red[k*16 + 4 + 2*pidx];
      im = red[k*16 + 5 + 2*pidx];
      if (i > j) im = -im;
    }
    g_Vp[(y*64 + (unsigned)tid)*F + f] = make_float2(re, im);
  }
}

// Per-f IP updates k=0..3 (sequential), fp64 cofactor solves, branch-free.
// Per-k batched prefetch of the 64 independent g_Vp float2 loads (R7-proven).
// it0: W starts as identity (no init_kernel needed). Zeroes BOTH r2 buffers
// so every launch (and replay) starts clean.
__global__ __launch_bounds__(64, 1) void update_kernel(int do_scale, int it0){
  int t = blockIdx.x*blockDim.x + threadIdx.x;
  // zero both r2 buffers (576 threads, coalesced, ~56 stores each)
  for (int j=t; j<KB; j+=576){ g_r2[0][j] = 0.0f; g_r2[1][j] = 0.0f; }
  int f = t;
  if (f >= F) return;
  cd W[4][4];
  if (it0){
    #pragma unroll
    for (int s=0;s<4;++s)
      #pragma unroll
      for (int c=0;c<4;++c) W[s][c] = mkcd(s==c ? 1.0 : 0.0, 0.0);
  } else {
    #pragma unroll
    for (int s=0;s<4;++s)
      #pragma unroll
      for (int c=0;c<4;++c){ float2 w = g_Wh[f*16+s*4+c]; W[s][c] = mkcd((double)w.x,(double)w.y); }
  }

  #pragma unroll
  for (int k=0;k<4;++k){
    float2 vp[NBC][16];
    #pragma unroll
    for (int y=0;y<NBC;++y)
      #pragma unroll
      for (int q=0;q<16;++q)
        vp[y][q] = g_Vp[(y*64 + k*16 + q)*F + f];
    cd Vk[4][4];
    #pragma unroll
    for (int i=0;i<4;++i)
      #pragma unroll
      for (int j=0;j<4;++j){
        int q = i*4 + j;
        float2 vv = make_float2(0.0f, 0.0f);
        #pragma unroll
        for (int y=0;y<NBC;++y){ vv.x += vp[y][q].x; vv.y += vp[y][q].y; }
        Vk[i][j] = mkcd((double)vv.x,(double)vv.y);
      }
    cd M[4][4];
    #pragma unroll
    for (int i=0;i<4;++i)
      #pragma unroll
      for (int j=0;j<4;++j){
        cd s = mkcd(0.0,0.0);
        #pragma unroll
        for (int c=0;c<4;++c) s = cadd(s, cmul(W[i][c], Vk[c][j]));
        M[i][j] = s;
      }
    cd x[4];
    invcol4(M, k, x);                  // x = inv(M)[:,k]
    cd w[4];
    #pragma unroll
    for (int c=0;c<4;++c) w[c] = conj_(x[c]);
    double dre = 0.0;
    #pragma unroll
    for (int j=0;j<4;++j){
      cd tj = mkcd(0.0,0.0);
      #pragma unroll
      for (int c=0;c<4;++c) tj = cadd(tj, cmul(w[c], Vk[c][j]));
      dre += tj.re*w[j].re + tj.im*w[j].im;   // Re(tj * conj(w_j))
    }
    double inv_denom = rsqrt(dre > 0.0 ? dre : 1e-300);
    #pragma unroll
    for (int c=0;c<4;++c) W[k][c] = mkcd(w[c].re*inv_denom, w[c].im*inv_denom);
  }
  #pragma unroll
  for (int s=0;s<4;++s)
    #pragma unroll
    for (int c=0;c<4;++c) g_Wh[f*16+s*4+c] = make_float2((float)W[s][c].re, (float)W[s][c].im);

  if (do_scale){
    cd x[4];
    invcol4(W, 0, x);   // x = inv(Wh)[:,0]
    #pragma unroll
    for (int s=0;s<4;++s) g_scale[f*4+s] = make_float2((float)x[s].re, (float)x[s].im);
  }
}

// out[s,f,b] = (Wh[f] X[:,f,b])[s] * scale[f,s]; interleaved (re,im) bf16 pairs
__global__ __launch_bounds__(256) void final_kernel(
    const float* __restrict__ Xr, const float* __restrict__ Xi,
    __hip_bfloat162* __restrict__ out){
  int b = blockIdx.x*blockDim.x + threadIdx.x;
  if (b >= B) return;
  int f0 = blockIdx.y*FCH, f1 = min(f0+FCH, F);
  for (int f=f0; f<f1; ++f){
    float xr[K], xi[K];
    #pragma unroll
    for (int c=0;c<K;++c){ int idx=c*FB + f*B + b; xr[c]=Xr[idx]; xi[c]=Xi[idx]; }
    const float2* w = g_Wh + f*16;
    #pragma unroll
    for (int s=0;s<K;++s){
      float yr=0.0f, yi=0.0f;
      #pragma unroll
      for (int c=0;c<K;++c){
        float2 ww = w[s*4+c];
        yr += ww.x*xr[c] - ww.y*xi[c];
        yi += ww.x*xi[c] + ww.y*xr[c];
      }
      float2 sc = g_scale[f*4+s];
      __hip_bfloat162 o;
      o.x = __float2bfloat16(yr*sc.x - yi*sc.y);
      o.y = __float2bfloat16(yr*sc.y + yi*sc.x);
      out[s*FB + f*B + b] = o;
    }
  }
}

// ---------------- launch ----------------------------------------------------
extern "C" void kernel_launch(void* const* d_in, const int* in_sizes, int n_in,
                              void* d_out, int out_size, void* d_ws, size_t ws_size,
                              hipStream_t stream){
  // Inputs arrive alphabetized: d_in[0]="Xi", d_in[1]="Xr".
  const float* Xr = (const float*)d_in[1];
  const float* Xi = (const float*)d_in[0];
  __hip_bfloat162* out = (__hip_bfloat162*)d_out;

  dim3 gD((B + 255)/256, NFC);          // (16, 65) demix/final
  dim3 gV(F, NBC);                      // (513, 4)
  for (int it=0; it<NIT; ++it){
    demix_part_kernel<<<gD, 256, 0, stream>>>(Xr, Xi, it & 1, it == 0 ? 1 : 0);
    v_kernel<<<gV, 256, 0, stream>>>(Xr, Xi, it & 1);
    update_kernel<<<(F + 63)/64, 64, 0, stream>>>(it == NIT-1 ? 1 : 0, it == 0 ? 1 : 0);
  }
  final_kernel<<<gD, 256, 0, stream>>>(Xr, Xi, out);
}

// Round 12
// 344.659 us; speedup vs baseline: 1.2551x; 1.2551x over previous
//
#include <hip/hip_runtime.h>
#include <hip/hip_bf16.h>
#include <math.h>

#define K 4
#define F 513
#define B 4000
#define NIT 5
#define FB (F*B)
#define KB (K*B)      // 16000
#define FCH 8         // f-chunk for demix/final (verified optimum; 4 regressed R10)
#define NFC 65        // ceil(513/8)
#define NBC 4         // b-chunks for v_kernel (verified optimum; 8 regressed R2)
#define BCH (B/NBC)   // 1000

// ---------------- persistent scratch: static device globals ------------------
__device__ float2 g_Wh[F*16];        // (F,4,4) complex fp32
__device__ float2 g_Vp[NBC*64*F];    // per-b-chunk partial V: (y, k*16+q, f)
__device__ float2 g_scale[F*4];      // (F,4) complex fp32
__device__ float  g_r2[2][KB];       // double-buffered r2 (atomicAdd from demix)

// ---------------- complex double helpers (tiny per-f solves only) -----------
struct cd { double re, im; };
__device__ inline cd mkcd(double r, double i){ cd z; z.re=r; z.im=i; return z; }
__device__ inline cd cmul(cd a, cd b){ return mkcd(a.re*b.re - a.im*b.im, a.re*b.im + a.im*b.re); }
__device__ inline cd cadd(cd a, cd b){ return mkcd(a.re+b.re, a.im+b.im); }
__device__ inline cd csub(cd a, cd b){ return mkcd(a.re-b.re, a.im-b.im); }
__device__ inline cd conj_(cd a){ return mkcd(a.re, -a.im); }
__device__ inline cd cdiv(cd a, cd b){
  double d = b.re*b.re + b.im*b.im;
  return mkcd((a.re*b.re + a.im*b.im)/d, (a.im*b.re - a.re*b.im)/d);
}

// x = inv(M)[:,kk] via cofactors (branch-free, no pivoting), full fp64.
__device__ inline void invcol4(const cd M[4][4], int kk, cd x[4]){
  int r0 = (kk==0)?1:0;
  int r1 = (kk<=1)?2:1;
  int r2 = (kk<=2)?3:2;
  cd cof[4];
  #pragma unroll
  for (int i=0;i<4;++i){
    int c0 = (i==0)?1:0;
    int c1 = (i<=1)?2:1;
    int c2 = (i<=2)?3:2;
    cd m = cadd(csub(cmul(M[r0][c0], csub(cmul(M[r1][c1],M[r2][c2]), cmul(M[r1][c2],M[r2][c1]))),
                     cmul(M[r0][c1], csub(cmul(M[r1][c0],M[r2][c2]), cmul(M[r1][c2],M[r2][c0])))),
                cmul(M[r0][c2], csub(cmul(M[r1][c0],M[r2][c1]), cmul(M[r1][c1],M[r2][c0]))));
    if ((kk+i)&1) m = mkcd(-m.re,-m.im);
    cof[i] = m;
  }
  cd det = mkcd(0.0,0.0);
  #pragma unroll
  for (int i=0;i<4;++i) det = cadd(det, cmul(M[kk][i], cof[i]));
  cd idet = cdiv(mkcd(1.0,0.0), det);
  #pragma unroll
  for (int i=0;i<4;++i) x[i] = cmul(cof[i], idet);
}

// ---------------- kernels ---------------------------------------------------

__global__ void init_kernel(){
  int t = blockIdx.x*blockDim.x + threadIdx.x;     // 33*256 = 8448 threads
  if (t < F*16){
    int sc = t & 15;
    g_Wh[t] = make_float2((sc>>2)==(sc&3) ? 1.0f : 0.0f, 0.0f);
  }
  for (int j=t; j<KB; j+=33*256) g_r2[0][j] = 0.0f;
}

// partial r2 accumulated straight into g_r2[pb] via atomicAdd (65 adders per
// address over the dispatch, 16000 distinct dwords -> negligible contention).
__global__ __launch_bounds__(256) void demix_part_kernel(
    const float* __restrict__ Xr, const float* __restrict__ Xi, int pb){
  int b = blockIdx.x*blockDim.x + threadIdx.x;
  if (b >= B) return;
  int y = blockIdx.y;
  int f0 = y*FCH, f1 = min(f0+FCH, F);
  float acc[K];
  #pragma unroll
  for (int s=0;s<K;++s) acc[s]=0.0f;
  for (int f=f0; f<f1; ++f){
    float xr[K], xi[K];
    #pragma unroll
    for (int c=0;c<K;++c){ int idx=c*FB + f*B + b; xr[c]=Xr[idx]; xi[c]=Xi[idx]; }
    const float2* w = g_Wh + f*16;
    #pragma unroll
    for (int s=0;s<K;++s){
      float yr=0.0f, yi=0.0f;
      #pragma unroll
      for (int c=0;c<K;++c){
        float2 ww = w[s*4+c];
        yr += ww.x*xr[c] - ww.y*xi[c];
        yi += ww.x*xi[c] + ww.y*xr[c];
      }
      acc[s] += yr*yr + yi*yi;
    }
  }
  #pragma unroll
  for (int s=0;s<K;++s) atomicAdd(&g_r2[pb][s*B + b], acc[s]);
}

// Partial V over a b-chunk: Vp[y,k,ij,f] = (1/B) sum_{b in chunk y} phi[k,b] p[ij](f,b)
// phi computed inline from g_r2[pb] (replaces the dedicated phi_kernel launch).
__global__ __launch_bounds__(256, 4) void v_kernel(
    const float* __restrict__ Xr, const float* __restrict__ Xi, int pb){
  int f = blockIdx.x;
  int y = blockIdx.y;
  int tid = threadIdx.x;
  float acc[64];
  #pragma unroll
  for (int q=0;q<64;++q) acc[q]=0.0f;

  int b0 = y*BCH;
  for (int b = b0 + tid; b < b0 + BCH; b += 256){
    float phi[K];
    #pragma unroll
    for (int k=0;k<K;++k) phi[k] = 0.5f / sqrtf(g_r2[pb][k*B+b]);
    float xr[K], xi[K];
    #pragma unroll
    for (int c=0;c<K;++c){ int idx=c*FB + f*B + b; xr[c]=Xr[idx]; xi[c]=Xi[idx]; }
    float p[16];
    #pragma unroll
    for (int i=0;i<4;++i) p[i] = xr[i]*xr[i] + xi[i]*xi[i];
    int s = 4;
    #pragma unroll
    for (int i=0;i<4;++i){
      #pragma unroll
      for (int j=i+1;j<4;++j){
        p[s++] = xr[i]*xr[j] + xi[i]*xi[j];
        p[s++] = xi[i]*xr[j] - xr[i]*xi[j];
      }
    }
    #pragma unroll
    for (int k=0;k<K;++k){
      #pragma unroll
      for (int q=0;q<16;++q) acc[k*16+q] += phi[k]*p[q];
    }
  }

  int lane = tid & 63, wave = tid >> 6;
  // Multi-value butterfly: 63 shfl_xor; after 6 steps lane l holds (in acc[0])
  // the wave-wide sum of original acc[l].
  #pragma unroll
  for (int d=0; d<6; ++d){
    const int sh = 1<<d;
    const bool hi = (lane & sh) != 0;
    #pragma unroll
    for (int m=0; m<(32>>d); ++m){
      float keep = hi ? acc[2*m+1] : acc[2*m];   // static indices: no scratch
      float send = hi ? acc[2*m]   : acc[2*m+1];
      acc[m] = keep + __shfl_xor(send, sh);
    }
  }

  __shared__ float part[4*64];
  __shared__ float red[64];
  part[wave*64 + lane] = acc[0];
  __syncthreads();
  if (tid < 64){
    red[tid] = (part[tid] + part[64+tid] + part[128+tid] + part[192+tid]) * (1.0f/B);
  }
  __syncthreads();
  if (tid < 64){
    int k = tid >> 4, ij = tid & 15, i = ij >> 2, j = ij & 3;
    float re, im;
    if (i == j){ re = red[k*16 + i]; im = 0.0f; }
    else {
      int a = min(i,j), c2 = max(i,j);
      int pidx = (a==0) ? (c2-1) : ((a==1) ? (c2+1) : 5);
      re = red[k*16 + 4 + 2*pidx];
      im = red[k*16 + 5 + 2*pidx];
      if (i > j) im = -im;
    }
    g_Vp[(y*64 + (unsigned)tid)*F + f] = make_float2(re, im);
  }
}

// Per-f IP updates k=0..3 (sequential), fp64 cofactor solves, branch-free.
// Per-k batched prefetch of the 64 independent g_Vp float2 loads (R7-proven).
// Also zeroes the other r2 buffer for the next iteration's demix atomics.
__global__ __launch_bounds__(64, 1) void update_kernel(int do_scale, int pb){
  int t = blockIdx.x*blockDim.x + threadIdx.x;
  // zero next r2 buffer (576 threads, coalesced, ~28 stores each)
  for (int j=t; j<KB; j+=576) g_r2[pb^1][j] = 0.0f;
  int f = t;
  if (f >= F) return;
  cd W[4][4];
  #pragma unroll
  for (int s=0;s<4;++s)
    #pragma unroll
    for (int c=0;c<4;++c){ float2 w = g_Wh[f*16+s*4+c]; W[s][c] = mkcd((double)w.x,(double)w.y); }

  #pragma unroll
  for (int k=0;k<4;++k){
    float2 vp[NBC][16];
    #pragma unroll
    for (int y=0;y<NBC;++y)
      #pragma unroll
      for (int q=0;q<16;++q)
        vp[y][q] = g_Vp[(y*64 + k*16 + q)*F + f];
    cd Vk[4][4];
    #pragma unroll
    for (int i=0;i<4;++i)
      #pragma unroll
      for (int j=0;j<4;++j){
        int q = i*4 + j;
        float2 vv = make_float2(0.0f, 0.0f);
        #pragma unroll
        for (int y=0;y<NBC;++y){ vv.x += vp[y][q].x; vv.y += vp[y][q].y; }
        Vk[i][j] = mkcd((double)vv.x,(double)vv.y);
      }
    cd M[4][4];
    #pragma unroll
    for (int i=0;i<4;++i)
      #pragma unroll
      for (int j=0;j<4;++j){
        cd s = mkcd(0.0,0.0);
        #pragma unroll
        for (int c=0;c<4;++c) s = cadd(s, cmul(W[i][c], Vk[c][j]));
        M[i][j] = s;
      }
    cd x[4];
    invcol4(M, k, x);                  // x = inv(M)[:,k]
    cd w[4];
    #pragma unroll
    for (int c=0;c<4;++c) w[c] = conj_(x[c]);
    double dre = 0.0;
    #pragma unroll
    for (int j=0;j<4;++j){
      cd tj = mkcd(0.0,0.0);
      #pragma unroll
      for (int c=0;c<4;++c) tj = cadd(tj, cmul(w[c], Vk[c][j]));
      dre += tj.re*w[j].re + tj.im*w[j].im;   // Re(tj * conj(w_j))
    }
    double inv_denom = rsqrt(dre > 0.0 ? dre : 1e-300);
    #pragma unroll
    for (int c=0;c<4;++c) W[k][c] = mkcd(w[c].re*inv_denom, w[c].im*inv_denom);
  }
  #pragma unroll
  for (int s=0;s<4;++s)
    #pragma unroll
    for (int c=0;c<4;++c) g_Wh[f*16+s*4+c] = make_float2((float)W[s][c].re, (float)W[s][c].im);

  if (do_scale){
    cd x[4];
    invcol4(W, 0, x);   // x = inv(Wh)[:,0]
    #pragma unroll
    for (int s=0;s<4;++s) g_scale[f*4+s] = make_float2((float)x[s].re, (float)x[s].im);
  }
}

// out[s,f,b] = (Wh[f] X[:,f,b])[s] * scale[f,s]; interleaved (re,im) bf16 pairs
__global__ __launch_bounds__(256) void final_kernel(
    const float* __restrict__ Xr, const float* __restrict__ Xi,
    __hip_bfloat162* __restrict__ out){
  int b = blockIdx.x*blockDim.x + threadIdx.x;
  if (b >= B) return;
  int f0 = blockIdx.y*FCH, f1 = min(f0+FCH, F);
  for (int f=f0; f<f1; ++f){
    float xr[K], xi[K];
    #pragma unroll
    for (int c=0;c<K;++c){ int idx=c*FB + f*B + b; xr[c]=Xr[idx]; xi[c]=Xi[idx]; }
    const float2* w = g_Wh + f*16;
    #pragma unroll
    for (int s=0;s<K;++s){
      float yr=0.0f, yi=0.0f;
      #pragma unroll
      for (int c=0;c<K;++c){
        float2 ww = w[s*4+c];
        yr += ww.x*xr[c] - ww.y*xi[c];
        yi += ww.x*xi[c] + ww.y*xr[c];
      }
      float2 sc = g_scale[f*4+s];
      __hip_bfloat162 o;
      o.x = __float2bfloat16(yr*sc.x - yi*sc.y);
      o.y = __float2bfloat16(yr*sc.y + yi*sc.x);
      out[s*FB + f*B + b] = o;
    }
  }
}

// ---------------- launch ----------------------------------------------------
extern "C" void kernel_launch(void* const* d_in, const int* in_sizes, int n_in,
                              void* d_out, int out_size, void* d_ws, size_t ws_size,
                              hipStream_t stream){
  // Inputs arrive alphabetized: d_in[0]="Xi", d_in[1]="Xr".
  const float* Xr = (const float*)d_in[1];
  const float* Xi = (const float*)d_in[0];
  __hip_bfloat162* out = (__hip_bfloat162*)d_out;

  init_kernel<<<33, 256, 0, stream>>>();
  dim3 gD((B + 255)/256, NFC);          // (16, 65)
  dim3 gV(F, NBC);                      // (513, 4)
  for (int it=0; it<NIT; ++it){
    demix_part_kernel<<<gD, 256, 0, stream>>>(Xr, Xi, it & 1);
    v_kernel<<<gV, 256, 0, stream>>>(Xr, Xi, it & 1);
    update_kernel<<<(F + 63)/64, 64, 0, stream>>>(it == NIT-1 ? 1 : 0, it & 1);
  }
  final_kernel<<<gD, 256, 0, stream>>>(Xr, Xi, out);
}